// Round 8
// baseline (289.081 us; speedup 1.0000x reference)
//
#include <hip/hip_runtime.h>

#define NN 4096

typedef __attribute__((ext_vector_type(8))) short short8;
typedef __attribute__((ext_vector_type(4))) float f32x4;

// fp32 -> bf16 round-to-nearest-even
static __device__ __forceinline__ unsigned short f2bf(float x) {
    unsigned int u = __float_as_uint(x);
    u += 0x7fffu + ((u >> 16) & 1u);
    return (unsigned short)(u >> 16);
}

// async global->LDS, 16 bytes per lane (dest = wave-uniform base + lane*16)
static __device__ __forceinline__ void load_lds16(const unsigned short* g, unsigned short* l) {
    __builtin_amdgcn_global_load_lds(
        (const __attribute__((address_space(1))) unsigned int*)g,
        (__attribute__((address_space(3))) unsigned int*)l,
        16, 0, 0);
}

// XOR-swizzled byte offset inside one 16KB K-subtile (256 rows x 32 k bf16, row = 64B).
// phys = logical ^ (((row>>1)&7)<<4): involution on 16B chunks within 128B row-pairs.
// Verified rounds 3/4/7: SQ_LDS_BANK_CONFLICT = 0.
static __device__ __forceinline__ int swz_byte(int row, int byte_in_row) {
    return (row * 64 + byte_in_row) ^ (((row >> 1) & 7) << 4);
}

// ---------------- fused pre-pass (r6 verbatim, harness-verified) ----------------
// A2: [bi(16)][kb32(128)][16KB tile 256 rows x 32 k, swizzled]; valid kb32 < (bi+1)*8.
// B2: [bjn(16)][kb32(128)][16KB tile 256 n-rows x 32 k (B^T), swizzled]; kb32 >= bjn*8.
// blocks [0,1088): B pack; [1088,2176): A pack; [2176,2401): zero C tiles
// (120 strict-upper + 105 lower D>=2; atomic tiles D>=4 are a subset).
__global__ __launch_bounds__(256) void prep_all(const float* __restrict__ A,
                                                const float* __restrict__ B,
                                                unsigned short* __restrict__ A2,
                                                unsigned short* __restrict__ B2,
                                                float* __restrict__ C) {
    __shared__ unsigned short tbf[32][264];   // 16.5 KB
    const int b   = blockIdx.x;
    const int tid = threadIdx.x;

    if (b < 1088) {
        // ---- pack B tile (bjn, kb32): n rows bjn*256..+255, k = kb32*32..+31, mask k>=n ----
        int rem = b, bjn;
        for (bjn = 0; bjn < 16; ++bjn) { int cnt = 128 - bjn * 8; if (rem < cnt) break; rem -= cnt; }
        const int kb = bjn * 8 + rem;
        #pragma unroll
        for (int p = 0; p < 8; ++p) {
            int id   = p * 256 + tid;
            int krow = id >> 6;              // 0..31
            int c4   = (id & 63) << 2;       // 0..252
            const float4 v = *(const float4*)(B + (size_t)(kb * 32 + krow) * NN + bjn * 256 + c4);
            tbf[krow][c4 + 0] = f2bf(v.x); tbf[krow][c4 + 1] = f2bf(v.y);
            tbf[krow][c4 + 2] = f2bf(v.z); tbf[krow][c4 + 3] = f2bf(v.w);
        }
        __syncthreads();
        unsigned short* out = B2 + (size_t)bjn * 1048576 + (size_t)kb * 8192;
        const int n  = tid;
        const int ng = bjn * 256 + n;
        #pragma unroll
        for (int kc = 0; kc < 4; ++kc) {
            short8 o;
            #pragma unroll
            for (int e = 0; e < 8; ++e) {
                int kg = kb * 32 + kc * 8 + e;
                o[e] = (kg >= ng) ? (short)tbf[kc * 8 + e][n] : (short)0;
            }
            *(short8*)&out[swz_byte(n, kc * 16) >> 1] = o;
        }
    } else if (b < 2176) {
        // ---- pack A tile (bi, kb32): rows bi*256..+255, k = kb32*32..+31, mask k<=i ----
        int rem = b - 1088, bi;
        for (bi = 0; bi < 16; ++bi) { int cnt = (bi + 1) * 8; if (rem < cnt) break; rem -= cnt; }
        const int kb = rem;
        unsigned short* out = A2 + (size_t)bi * 1048576 + (size_t)kb * 8192;
        #pragma unroll
        for (int p = 0; p < 8; ++p) {
            int id  = p * 256 + tid;
            int row = id >> 3;               // 0..255
            int c4  = (id & 7) << 2;         // 0..28
            const int gi = bi * 256 + row;
            const int kg = kb * 32 + c4;
            const float4 v = *(const float4*)(A + (size_t)gi * NN + kg);
            ushort4 o;
            o.x = (kg + 0 <= gi) ? f2bf(v.x) : (unsigned short)0;
            o.y = (kg + 1 <= gi) ? f2bf(v.y) : (unsigned short)0;
            o.z = (kg + 2 <= gi) ? f2bf(v.z) : (unsigned short)0;
            o.w = (kg + 3 <= gi) ? f2bf(v.w) : (unsigned short)0;
            *(ushort4*)&out[swz_byte(row, c4 * 2) >> 1] = o;
        }
    } else {
        // ---- zero C tiles: 120 strict-upper + 105 lower (D>=2) ----
        int u = b - 2176;
        int ti, tj;
        if (u < 120) {
            for (tj = 1; tj < 16; ++tj) { if (u < tj) { ti = u; break; } u -= tj; }
        } else {
            u -= 120;
            int d2;
            for (d2 = 2; d2 < 16; ++d2) { int cnt = 16 - d2; if (u < cnt) break; u -= cnt; }
            tj = u; ti = u + d2;
        }
        const float4 z = make_float4(0.f, 0.f, 0.f, 0.f);
        #pragma unroll
        for (int it = 0; it < 64; ++it) {
            int idx = it * 256 + tid;
            int rr  = idx >> 6;
            int c4  = (idx & 63) << 2;
            *(float4*)&C[(size_t)(ti * 256 + rr) * NN + tj * 256 + c4] = z;
        }
    }
}

// ---------------- main GEMM: 256x256, BK=64, m201-style 8-phase dbuf pipeline ----------------
// 260 units (r3-verified decode): tile (bi,bj), D=bi-bj, m=ceil((D+1)/4) chunks, XCD-chunked.
// 8 waves (2Mx4N), 512 thr, LDS 128KB (2 bufs x 32KB A + 32KB B) -> 1 block/CU.
// Per K-tile: 4 quadrant-phases {12 ds_read || prefetch -> barrier -> lgkm(0) -> 16 MFMA ->
// barrier}; counted wait once per K-tile (vmcnt at boundary; loads issued 2-3 phases earlier).
// Race-free distance-1 staging: stages target buf^1, whose readers crossed the prev
// iteration's final barrier before any stage issues.
__global__ __launch_bounds__(512, 2) void gemm_tril8(const unsigned short* __restrict__ A2,
                                                     const unsigned short* __restrict__ B2,
                                                     float* __restrict__ C) {
    const int tid = threadIdx.x;

    // bijective XCD-chunked map for 260 blocks (r3 verbatim)
    const int bidx = (int)blockIdx.x;
    const int xcd = bidx & 7, ix = bidx >> 3;
    int u = (xcd < 4 ? xcd * 33 : 132 + (xcd - 4) * 32) + ix;

    // decode unit (deepest-D first) -> (D, tile, chunk); m = ceil((D+1)/4)
    int D, m = 1, rem = u;
    for (D = 15; D >= 0; --D) {
        m = (D + 4) >> 2;
        int cnt = (16 - D) * m;
        if (rem < cnt) break;
        rem -= cnt;
    }
    const int blk = rem / m;
    const int c   = rem - blk * m;
    const int bj = blk, bi = blk + D;
    const int S64 = (D + 1) * 4;
    const int kt0 = bj * 4 + (c * S64) / m;
    const int kt1 = bj * 4 + ((c + 1) * S64) / m;
    const int nkt = kt1 - kt0;

    __shared__ __attribute__((aligned(16))) unsigned short As[2][16384];  // 2 x 32KB
    __shared__ __attribute__((aligned(16))) unsigned short Bs[2][16384];  // 2 x 32KB

    const int lane = tid & 63;
    const int w    = tid >> 6;               // 0..7
    const int wm   = w >> 2, wn = w & 3;     // 2 x 4 wave grid: 128 x 64 per wave
    const int l15  = lane & 15, quad = lane >> 4;

    f32x4 acc[8][4];
    const f32x4 zero4 = {0.f, 0.f, 0.f, 0.f};
    #pragma unroll
    for (int i = 0; i < 8; ++i)
        #pragma unroll
        for (int j = 0; j < 4; ++j) acc[i][j] = zero4;

    const unsigned short* Atile = A2 + (size_t)bi * 1048576 + tid * 8;
    const unsigned short* Btile = B2 + (size_t)bj * 1048576 + tid * 8;

    // precomputed swizzled LDS offsets (ushort units) per fragment row
    int aoff[8], boff[4];
    #pragma unroll
    for (int mt = 0; mt < 8; ++mt) aoff[mt] = swz_byte(wm * 128 + mt * 16 + l15, quad * 16) >> 1;
    #pragma unroll
    for (int nt = 0; nt < 4; ++nt) boff[nt] = swz_byte(wn * 64 + nt * 16 + l15, quad * 16) >> 1;

    // prologue: stage K-tile kt0 into buf 0 (8 x global_load_lds)
    {
        const unsigned short* ga = Atile + (size_t)kt0 * 16384;
        const unsigned short* gb = Btile + (size_t)kt0 * 16384;
        #pragma unroll
        for (int r = 0; r < 4; ++r) load_lds16(ga + r * 4096, &As[0][tid * 8 + r * 4096]);
        #pragma unroll
        for (int r = 0; r < 4; ++r) load_lds16(gb + r * 4096, &Bs[0][tid * 8 + r * 4096]);
    }

    for (int i = 0; i < nkt; ++i) {
        const int buf = i & 1;
        const unsigned short* As_b = As[buf];
        const unsigned short* Bs_b = Bs[buf];
        // boundary: my stages for this buf (issued 2-3 phases ago) must have landed,
        // then barrier so every wave's stages are visible. Counted-in-effect: nothing
        // else is in flight at this point (distance-1), so no future prefetch is drained.
        asm volatile("s_waitcnt vmcnt(0)" ::: "memory");
        __builtin_amdgcn_s_barrier();
        __builtin_amdgcn_sched_barrier(0);

        const bool pf = (i + 1 < nkt);
        const unsigned short* gaN = Atile + (size_t)(kt0 + i + 1) * 16384;
        const unsigned short* gbN = Btile + (size_t)(kt0 + i + 1) * 16384;
        unsigned short* AsN = As[buf ^ 1];
        unsigned short* BsN = Bs[buf ^ 1];

        #pragma unroll
        for (int q = 0; q < 4; ++q) {
            const int mg = q >> 1, ng = q & 1;
            // prefetch next K-tile, front-loaded: A halves in phase 0, B halves in phase 1
            if (q == 0 && pf) {
                #pragma unroll
                for (int r = 0; r < 4; ++r) load_lds16(gaN + r * 4096, &AsN[tid * 8 + r * 4096]);
            }
            if (q == 1 && pf) {
                #pragma unroll
                for (int r = 0; r < 4; ++r) load_lds16(gbN + r * 4096, &BsN[tid * 8 + r * 4096]);
            }
            // ds-load this phase's register subtile: 8 A-frags + 4 B-frags (12 ds_read_b128)
            short8 af[4][2], bfr[2][2];
            #pragma unroll
            for (int t2 = 0; t2 < 4; ++t2)
                #pragma unroll
                for (int h = 0; h < 2; ++h)
                    af[t2][h] = *(const short8*)&As_b[h * 8192 + aoff[mg * 4 + t2]];
            #pragma unroll
            for (int n2 = 0; n2 < 2; ++n2)
                #pragma unroll
                for (int h = 0; h < 2; ++h)
                    bfr[n2][h] = *(const short8*)&Bs_b[h * 8192 + boff[ng * 2 + n2]];
            __builtin_amdgcn_s_barrier();
            asm volatile("s_waitcnt lgkmcnt(0)" ::: "memory");
            __builtin_amdgcn_sched_barrier(0);
            __builtin_amdgcn_s_setprio(1);
            #pragma unroll
            for (int t2 = 0; t2 < 4; ++t2)
                #pragma unroll
                for (int n2 = 0; n2 < 2; ++n2) {
                    acc[mg*4+t2][ng*2+n2] = __builtin_amdgcn_mfma_f32_16x16x32_bf16(
                        af[t2][0], bfr[n2][0], acc[mg*4+t2][ng*2+n2], 0, 0, 0);
                    acc[mg*4+t2][ng*2+n2] = __builtin_amdgcn_mfma_f32_16x16x32_bf16(
                        af[t2][1], bfr[n2][1], acc[mg*4+t2][ng*2+n2], 0, 0, 0);
                }
            __builtin_amdgcn_s_setprio(0);
            __builtin_amdgcn_s_barrier();
        }
    }

    // epilogue (r4 verbatim): C/D layout col=lane&15, row=quad*4+reg (m89-verified)
    if (m == 1) {
        // D<=3: sole owner, direct store (diagonal mask only when D==0)
        #pragma unroll
        for (int mt = 0; mt < 8; ++mt) {
            #pragma unroll
            for (int nt2 = 0; nt2 < 4; ++nt2) {
                const int gj  = bj * 256 + wn * 64 + nt2 * 16 + l15;
                const int gi0 = bi * 256 + wm * 128 + mt * 16 + quad * 4;
                #pragma unroll
                for (int rr = 0; rr < 4; ++rr) {
                    int gi = gi0 + rr;
                    float v = acc[mt][nt2][rr];
                    C[(size_t)gi * NN + gj] = (D > 0 || gi >= gj) ? v : 0.f;
                }
            }
        }
    } else {
        // partial contribution: tile pre-zeroed in prep; D>=4 so strictly lower, no mask
        #pragma unroll
        for (int mt = 0; mt < 8; ++mt) {
            #pragma unroll
            for (int nt2 = 0; nt2 < 4; ++nt2) {
                const int gj  = bj * 256 + wn * 64 + nt2 * 16 + l15;
                const int gi0 = bi * 256 + wm * 128 + mt * 16 + quad * 4;
                #pragma unroll
                for (int rr = 0; rr < 4; ++rr) {
                    int gi = gi0 + rr;
                    atomicAdd(&C[(size_t)gi * NN + gj], acc[mt][nt2][rr]);
                }
            }
        }
    }
}

// ---------------- fallback (ws too small): fp32 LDS-tiled, correct-but-slow ----------------
__global__ void gemm_fallback(const float* __restrict__ A, const float* __restrict__ B,
                              float* __restrict__ C) {
    const int bi = blockIdx.y, bj = blockIdx.x;
    const int ty = threadIdx.y, tx = threadIdx.x;
    const int gi = bi * 32 + ty, gj = bj * 32 + tx;
    if (bi < bj) { C[(size_t)gi * NN + gj] = 0.f; return; }
    __shared__ float As[32][33], Bs[32][33];
    float s = 0.f;
    for (int kt = bj; kt <= bi; ++kt) {
        const int k = kt * 32;
        float av = A[(size_t)gi * NN + k + tx];
        As[ty][tx] = (k + tx <= gi) ? av : 0.f;
        float bv = B[(size_t)(k + ty) * NN + gj];
        Bs[ty][tx] = (k + ty >= gj) ? bv : 0.f;
        __syncthreads();
        #pragma unroll
        for (int kk = 0; kk < 32; ++kk) s += As[ty][kk] * Bs[kk][tx];
        __syncthreads();
    }
    C[(size_t)gi * NN + gj] = (gi >= gj) ? s : 0.f;
}

extern "C" void kernel_launch(void* const* d_in, const int* in_sizes, int n_in,
                              void* d_out, int out_size, void* d_ws, size_t ws_size,
                              hipStream_t stream) {
    const float* A = (const float*)d_in[0];
    const float* B = (const float*)d_in[1];
    float* C = (float*)d_out;

    const size_t need = (size_t)2 * NN * NN * sizeof(unsigned short);  // 64 MB
    if (ws_size >= need) {
        unsigned short* A2 = (unsigned short*)d_ws;
        unsigned short* B2 = A2 + (size_t)NN * NN;
        prep_all<<<dim3(2401), dim3(256), 0, stream>>>(A, B, A2, B2, C);
        gemm_tril8<<<dim3(260), dim3(512), 0, stream>>>(A2, B2, C);
    } else {
        gemm_fallback<<<dim3(128, 128), dim3(32, 32), 0, stream>>>(A, B, C);
    }
}